// Round 1
// baseline (698.485 us; speedup 1.0000x reference)
//
#include <hip/hip_runtime.h>

#define EMBED 1024
#define MLP   2048
#define NE    8
#define NTOK  8192                      // 4*2048 tokens
#define RMAX  (2*NTOK + NE*128)         // 17408 gathered rows max (128-pad per expert)

typedef _Float16 f16x8 __attribute__((ext_vector_type(8)));
typedef _Float16 f16x4 __attribute__((ext_vector_type(4)));
typedef float    f32x4 __attribute__((ext_vector_type(4)));

// ---------------------------------------------------------------------------
// Router: one wave per token. logits = x[t] @ gate_w (fp32), top-2, weights =
// softmax over the two selected logits (== renormalized full softmax).
// ---------------------------------------------------------------------------
__global__ __launch_bounds__(256) void router_kernel(
    const float* __restrict__ x, const float* __restrict__ gw,
    int* __restrict__ sel_e, float* __restrict__ sel_w, int* __restrict__ counts)
{
  __shared__ float gwt[NE * EMBED];   // transposed gate: gwt[e][i]
  __shared__ int cnt[NE];
  int tid = threadIdx.x;
  for (int idx = tid; idx < NE * EMBED; idx += 256) {
    int i = idx >> 3, e = idx & 7;
    gwt[e * EMBED + i] = gw[idx];     // gw is [EMBED][NE]
  }
  if (tid < NE) cnt[tid] = 0;
  __syncthreads();

  int lane = tid & 63, wv = tid >> 6;
  int t = blockIdx.x * 4 + wv;
  const float4* xr = (const float4*)(x + (size_t)t * EMBED);
  const float4* gt4 = (const float4*)gwt;
  float acc[NE];
  #pragma unroll
  for (int e = 0; e < NE; ++e) acc[e] = 0.f;
  #pragma unroll
  for (int c = 0; c < 4; ++c) {
    float4 xv = xr[c * 64 + lane];
    #pragma unroll
    for (int e = 0; e < NE; ++e) {
      float4 gv = gt4[e * 256 + c * 64 + lane];
      acc[e] += xv.x * gv.x + xv.y * gv.y + xv.z * gv.z + xv.w * gv.w;
    }
  }
  #pragma unroll
  for (int off = 1; off < 64; off <<= 1) {
    #pragma unroll
    for (int e = 0; e < NE; ++e) acc[e] += __shfl_xor(acc[e], off);
  }
  if (lane == 0) {
    int e0 = 0; float l0 = acc[0];
    #pragma unroll
    for (int e = 1; e < NE; ++e) if (acc[e] > l0) { l0 = acc[e]; e0 = e; }
    int e1 = -1; float l1 = -1e30f;
    #pragma unroll
    for (int e = 0; e < NE; ++e) if (e != e0 && acc[e] > l1) { l1 = acc[e]; e1 = e; }
    float w0 = 1.f / (1.f + expf(l1 - l0));   // softmax over {l0,l1}
    sel_e[2 * t] = e0;     sel_w[2 * t] = w0;
    sel_e[2 * t + 1] = e1; sel_w[2 * t + 1] = 1.f - w0;
    atomicAdd(&cnt[e0], 1); atomicAdd(&cnt[e1], 1);
  }
  __syncthreads();
  if (tid < NE && cnt[tid]) atomicAdd(&counts[tid], cnt[tid]);
}

// ---------------------------------------------------------------------------
// Offsets: 128-aligned segment starts per expert; cursor = start.
// ---------------------------------------------------------------------------
__global__ void offsets_kernel(const int* __restrict__ counts,
                               int* __restrict__ offs, int* __restrict__ cursor)
{
  if (threadIdx.x == 0) {
    int o = 0;
    for (int e = 0; e < NE; ++e) {
      offs[e] = o; cursor[e] = o;
      o += (counts[e] + 127) & ~127;
    }
    offs[NE] = o;
  }
}

// ---------------------------------------------------------------------------
// Assign: scatter (token, weight) into per-expert row lists. Wave-aggregated
// atomics (16K raw atomics on 8 counters would serialize).
// ---------------------------------------------------------------------------
__global__ __launch_bounds__(256) void assign_kernel(
    const int* __restrict__ sel_e, const float* __restrict__ sel_w,
    int* __restrict__ cursor, int* __restrict__ rowtok, float* __restrict__ rowcoef)
{
  int t = blockIdx.x * 256 + threadIdx.x;
  int lane = threadIdx.x & 63;
  #pragma unroll
  for (int k = 0; k < 2; ++k) {
    int e = sel_e[2 * t + k];
    float w = sel_w[2 * t + k];
    for (int xch = 0; xch < NE; ++xch) {
      unsigned long long m = __ballot(e == xch);
      if (e == xch) {
        int leader = __ffsll((unsigned long long)m) - 1;
        int base = 0;
        if (lane == leader) base = atomicAdd(&cursor[xch], (int)__popcll(m));
        base = __shfl(base, leader);
        int pos = base + (int)__popcll(m & ((1ull << lane) - 1));
        rowtok[pos] = t;
        rowcoef[pos] = w;
      }
    }
  }
}

// ---------------------------------------------------------------------------
// Gather: xg[row] = fp16(x[rowtok[row]]); zeros for padding rows (tok = -1).
// One block per row, float4 in / f16x4 out.
// ---------------------------------------------------------------------------
__global__ __launch_bounds__(256) void gather_kernel(
    const float* __restrict__ x, const int* __restrict__ rowtok,
    _Float16* __restrict__ xg)
{
  int r = blockIdx.x;
  int tok = rowtok[r];
  int t4 = threadIdx.x * 4;
  _Float16* dst = xg + (size_t)r * EMBED + t4;
  if (tok >= 0) {
    float4 v = *(const float4*)(x + (size_t)tok * EMBED + t4);
    f16x4 h; h.x = (_Float16)v.x; h.y = (_Float16)v.y; h.z = (_Float16)v.z; h.w = (_Float16)v.w;
    *(f16x4*)dst = h;
  } else {
    f16x4 z = {(_Float16)0.f, (_Float16)0.f, (_Float16)0.f, (_Float16)0.f};
    *(f16x4*)dst = z;
  }
}

// ---------------------------------------------------------------------------
// Transpose+cast: in fp32 [K][N] -> out fp16 [N][K], per expert (blockIdx.z).
// 64x64 tile via LDS (pitch 65 -> conflict-free column reads, verified math).
// ---------------------------------------------------------------------------
__global__ __launch_bounds__(256) void transpose_cast_kernel(
    const float* __restrict__ in, _Float16* __restrict__ out, int K, int N)
{
  const float* src = in + (size_t)blockIdx.z * K * N;
  _Float16* dst = out + (size_t)blockIdx.z * K * N;
  int k0 = blockIdx.x * 64, n0 = blockIdx.y * 64;
  __shared__ float tile[64][65];
  int t = threadIdx.x;
  int r = t >> 4, c4 = (t & 15) * 4;
  #pragma unroll
  for (int i = 0; i < 4; ++i) {
    float4 v = *(const float4*)(src + (size_t)(k0 + r + 16 * i) * N + n0 + c4);
    tile[r + 16 * i][c4 + 0] = v.x;
    tile[r + 16 * i][c4 + 1] = v.y;
    tile[r + 16 * i][c4 + 2] = v.z;
    tile[r + 16 * i][c4 + 3] = v.w;
  }
  __syncthreads();
  int kk8 = (t & 7) * 8, nIdx = t >> 3;
  #pragma unroll
  for (int i = 0; i < 2; ++i) {
    int n = nIdx + 32 * i;
    f16x8 h;
    #pragma unroll
    for (int j = 0; j < 8; ++j) h[j] = (_Float16)tile[kk8 + j][n];
    *(f16x8*)(dst + (size_t)(n0 + n) * K + k0 + kk8) = h;
  }
}

// ---------------------------------------------------------------------------
// Expert-segment resolution: unique e with offs[e] <= r0 < offs[e+1]
// (segments are 128-aligned so a 128-row tile never straddles experts).
// ---------------------------------------------------------------------------
__device__ __forceinline__ int resolve_expert(const int* __restrict__ offs, int r0)
{
  int e = 0;
  #pragma unroll
  for (int q = 0; q < NE - 1; ++q) if (r0 >= offs[q + 1]) e = q + 1;
  return e;
}

// ---------------------------------------------------------------------------
// GEMM1 (fused SwiGLU): h = silu(xg@w1t^T) * (xg@w3t^T) * coef, fp16 out.
// 128x128 tile, BK=32, 4 waves x (4x4 of 16x16x32 mfma) x 2 B-matrices.
// A layout [row][k] k-contig; B layouts [n][k] k-contig (pre-transposed).
// LDS staged as 16B chunks: chunk c = row*4 + kquarter, addr = c*16B
// (conflict-free writes; frag reads are ds_read_b128, banks uniform).
// ---------------------------------------------------------------------------
__global__ __launch_bounds__(256, 2) void gemm1_kernel(
    const _Float16* __restrict__ xg, const _Float16* __restrict__ w1t,
    const _Float16* __restrict__ w3t, const float* __restrict__ rowcoef,
    const int* __restrict__ offs, _Float16* __restrict__ hb)
{
  int r0 = blockIdx.x * 128;
  if (r0 >= offs[NE]) return;
  int e = resolve_expert(offs, r0);
  int n0 = blockIdx.y * 128;
  const _Float16* B1 = w1t + (size_t)e * MLP * EMBED;
  const _Float16* B3 = w3t + (size_t)e * MLP * EMBED;

  __shared__ __align__(16) _Float16 As[128 * 32];
  __shared__ __align__(16) _Float16 Bs1[128 * 32];
  __shared__ __align__(16) _Float16 Bs3[128 * 32];

  int tid = threadIdx.x, lane = tid & 63, wv = tid >> 6;
  int wm = (wv & 1) << 6, wn = (wv >> 1) << 6;
  int l16 = lane & 15, quad = lane >> 4;

  f32x4 acc1[4][4], acc3[4][4];
  f32x4 z4 = {0.f, 0.f, 0.f, 0.f};
  #pragma unroll
  for (int i = 0; i < 4; ++i)
    #pragma unroll
    for (int j = 0; j < 4; ++j) { acc1[i][j] = z4; acc3[i][j] = z4; }

  for (int kk = 0; kk < EMBED; kk += 32) {
    __syncthreads();
    #pragma unroll
    for (int p = 0; p < 2; ++p) {
      int c = p * 256 + tid;
      int row = c >> 2, kp = (c & 3) << 3;
      *(f16x8*)(As  + c * 8) = *(const f16x8*)(xg + (size_t)(r0 + row) * EMBED + kk + kp);
      *(f16x8*)(Bs1 + c * 8) = *(const f16x8*)(B1 + (size_t)(n0 + row) * EMBED + kk + kp);
      *(f16x8*)(Bs3 + c * 8) = *(const f16x8*)(B3 + (size_t)(n0 + row) * EMBED + kk + kp);
    }
    __syncthreads();
    f16x8 af[4], b1f[4], b3f[4];
    #pragma unroll
    for (int i = 0; i < 4; ++i)
      af[i] = *(const f16x8*)(As + (wm + 16 * i + l16) * 32 + quad * 8);
    #pragma unroll
    for (int j = 0; j < 4; ++j) {
      b1f[j] = *(const f16x8*)(Bs1 + (wn + 16 * j + l16) * 32 + quad * 8);
      b3f[j] = *(const f16x8*)(Bs3 + (wn + 16 * j + l16) * 32 + quad * 8);
    }
    #pragma unroll
    for (int i = 0; i < 4; ++i)
      #pragma unroll
      for (int j = 0; j < 4; ++j) {
        acc1[i][j] = __builtin_amdgcn_mfma_f32_16x16x32_f16(af[i], b1f[j], acc1[i][j], 0, 0, 0);
        acc3[i][j] = __builtin_amdgcn_mfma_f32_16x16x32_f16(af[i], b3f[j], acc3[i][j], 0, 0, 0);
      }
  }

  // Epilogue: h = silu(g)*u*coef[row]; C/D layout col=lane&15, row=quad*4+reg.
  #pragma unroll
  for (int i = 0; i < 4; ++i) {
    int mb = r0 + wm + 16 * i + quad * 4;
    float cf[4];
    #pragma unroll
    for (int rg = 0; rg < 4; ++rg) cf[rg] = rowcoef[mb + rg];
    #pragma unroll
    for (int j = 0; j < 4; ++j) {
      int col = n0 + wn + 16 * j + l16;
      #pragma unroll
      for (int rg = 0; rg < 4; ++rg) {
        float g = acc1[i][j][rg], u = acc3[i][j][rg];
        float h = g * u * cf[rg] / (1.f + __expf(-g));
        hb[(size_t)(mb + rg) * MLP + col] = (_Float16)h;
      }
    }
  }
}

// ---------------------------------------------------------------------------
// GEMM2: out[tok] += h @ w2t^T (w2t is [n][k] fp16, K=2048). Scatter via
// fp32 atomics (exactly 2 contributions per token).
// ---------------------------------------------------------------------------
__global__ __launch_bounds__(256, 2) void gemm2_kernel(
    const _Float16* __restrict__ hb, const _Float16* __restrict__ w2t,
    const int* __restrict__ rowtok, const int* __restrict__ offs,
    float* __restrict__ out)
{
  int r0 = blockIdx.x * 128;
  if (r0 >= offs[NE]) return;
  int e = resolve_expert(offs, r0);
  int n0 = blockIdx.y * 128;
  const _Float16* B = w2t + (size_t)e * EMBED * MLP;

  __shared__ __align__(16) _Float16 As[128 * 32];
  __shared__ __align__(16) _Float16 Bs[128 * 32];

  int tid = threadIdx.x, lane = tid & 63, wv = tid >> 6;
  int wm = (wv & 1) << 6, wn = (wv >> 1) << 6;
  int l16 = lane & 15, quad = lane >> 4;

  f32x4 acc[4][4];
  f32x4 z4 = {0.f, 0.f, 0.f, 0.f};
  #pragma unroll
  for (int i = 0; i < 4; ++i)
    #pragma unroll
    for (int j = 0; j < 4; ++j) acc[i][j] = z4;

  for (int kk = 0; kk < MLP; kk += 32) {
    __syncthreads();
    #pragma unroll
    for (int p = 0; p < 2; ++p) {
      int c = p * 256 + tid;
      int row = c >> 2, kp = (c & 3) << 3;
      *(f16x8*)(As + c * 8) = *(const f16x8*)(hb + (size_t)(r0 + row) * MLP + kk + kp);
      *(f16x8*)(Bs + c * 8) = *(const f16x8*)(B  + (size_t)(n0 + row) * MLP + kk + kp);
    }
    __syncthreads();
    f16x8 af[4], bf[4];
    #pragma unroll
    for (int i = 0; i < 4; ++i)
      af[i] = *(const f16x8*)(As + (wm + 16 * i + l16) * 32 + quad * 8);
    #pragma unroll
    for (int j = 0; j < 4; ++j)
      bf[j] = *(const f16x8*)(Bs + (wn + 16 * j + l16) * 32 + quad * 8);
    #pragma unroll
    for (int i = 0; i < 4; ++i)
      #pragma unroll
      for (int j = 0; j < 4; ++j)
        acc[i][j] = __builtin_amdgcn_mfma_f32_16x16x32_f16(af[i], bf[j], acc[i][j], 0, 0, 0);
  }

  #pragma unroll
  for (int i = 0; i < 4; ++i) {
    int mb = r0 + wm + 16 * i + quad * 4;
    int tk[4];
    #pragma unroll
    for (int rg = 0; rg < 4; ++rg) tk[rg] = rowtok[mb + rg];
    #pragma unroll
    for (int j = 0; j < 4; ++j) {
      int col = n0 + wn + 16 * j + l16;
      #pragma unroll
      for (int rg = 0; rg < 4; ++rg)
        if (tk[rg] >= 0)
          atomicAdd(out + (size_t)tk[rg] * EMBED + col, acc[i][j][rg]);
    }
  }
}

// ---------------------------------------------------------------------------
extern "C" void kernel_launch(void* const* d_in, const int* in_sizes, int n_in,
                              void* d_out, int out_size, void* d_ws, size_t ws_size,
                              hipStream_t stream)
{
  (void)in_sizes; (void)n_in; (void)ws_size;
  const float* x  = (const float*)d_in[0];
  const float* gw = (const float*)d_in[1];
  const float* w1 = (const float*)d_in[2];
  const float* w2 = (const float*)d_in[3];   // NOTE: dict order is w1, w2, w3
  const float* w3 = (const float*)d_in[4];
  float* out = (float*)d_out;
  char* ws = (char*)d_ws;

  size_t o = 0;
  auto alloc = [&](size_t bytes) { size_t r = o; o = (o + bytes + 255) & ~255ULL; return r; };
  const size_t wbytes = (size_t)NE * MLP * EMBED * 2;
  _Float16* w1t = (_Float16*)(ws + alloc(wbytes));
  _Float16* w3t = (_Float16*)(ws + alloc(wbytes));
  _Float16* w2t = (_Float16*)(ws + alloc(wbytes));
  _Float16* xg  = (_Float16*)(ws + alloc((size_t)RMAX * EMBED * 2));
  _Float16* hb  = (_Float16*)(ws + alloc((size_t)RMAX * MLP * 2));
  int*   rowtok  = (int*)(ws + alloc((size_t)RMAX * 4));
  float* rowcoef = (float*)(ws + alloc((size_t)RMAX * 4));
  int*   sel_e   = (int*)(ws + alloc((size_t)2 * NTOK * 4));
  float* sel_w   = (float*)(ws + alloc((size_t)2 * NTOK * 4));
  int*   meta    = (int*)(ws + alloc(256));
  int* counts = meta;          // [8]
  int* offs   = meta + 8;      // [9]
  int* cursor = meta + 17;     // [8]

  hipMemsetAsync(out, 0, (size_t)out_size * 4, stream);
  hipMemsetAsync(meta, 0, 256, stream);
  hipMemsetAsync(rowtok, 0xFF, (size_t)RMAX * 4, stream);   // -1 = padding
  hipMemsetAsync(rowcoef, 0, (size_t)RMAX * 4, stream);

  transpose_cast_kernel<<<dim3(EMBED / 64, MLP / 64, NE), 256, 0, stream>>>(w1, w1t, EMBED, MLP);
  transpose_cast_kernel<<<dim3(EMBED / 64, MLP / 64, NE), 256, 0, stream>>>(w3, w3t, EMBED, MLP);
  transpose_cast_kernel<<<dim3(MLP / 64, EMBED / 64, NE), 256, 0, stream>>>(w2, w2t, MLP, EMBED);

  router_kernel<<<NTOK / 4, 256, 0, stream>>>(x, gw, sel_e, sel_w, counts);
  offsets_kernel<<<1, 64, 0, stream>>>(counts, offs, cursor);
  assign_kernel<<<NTOK / 256, 256, 0, stream>>>(sel_e, sel_w, cursor, rowtok, rowcoef);
  gather_kernel<<<RMAX, 256, 0, stream>>>(x, rowtok, xg);

  gemm1_kernel<<<dim3(RMAX / 128, MLP / 128), 256, 0, stream>>>(xg, w1t, w3t, rowcoef, offs, hb);
  gemm2_kernel<<<dim3(RMAX / 128, EMBED / 128), 256, 0, stream>>>(hb, w2t, rowtok, offs, out);
}

// Round 2
// 678.360 us; speedup vs baseline: 1.0297x; 1.0297x over previous
//
#include <hip/hip_runtime.h>

#define EMBED 1024
#define MLP   2048
#define NE    8
#define NTOK  8192                      // 4*2048 tokens
#define RMAX  (2*NTOK + NE*128)         // 17408 gathered rows max (128-pad per expert)

typedef _Float16 f16x8 __attribute__((ext_vector_type(8)));
typedef _Float16 f16x4 __attribute__((ext_vector_type(4)));
typedef float    f32x4 __attribute__((ext_vector_type(4)));

// Async 16B global->LDS copy. LDS dest is wave-uniform base + lane*16 (HW
// constraint); we exploit that by permuting WHICH global chunk each lane
// fetches (XOR swizzle) instead of where it lands.
__device__ __forceinline__ void async_copy16(const void* g, void* l) {
  __builtin_amdgcn_global_load_lds(
      (const __attribute__((address_space(1))) unsigned int*)g,
      (__attribute__((address_space(3))) unsigned int*)l, 16, 0, 0);
}

// ---------------------------------------------------------------------------
// Router: one wave per token. logits = x[t] @ gate_w (fp32), top-2, weights =
// softmax over the two selected logits (== renormalized full softmax).
// ---------------------------------------------------------------------------
__global__ __launch_bounds__(256) void router_kernel(
    const float* __restrict__ x, const float* __restrict__ gw,
    int* __restrict__ sel_e, float* __restrict__ sel_w, int* __restrict__ counts)
{
  __shared__ float gwt[NE * EMBED];   // transposed gate: gwt[e][i]
  __shared__ int cnt[NE];
  int tid = threadIdx.x;
  for (int idx = tid; idx < NE * EMBED; idx += 256) {
    int i = idx >> 3, e = idx & 7;
    gwt[e * EMBED + i] = gw[idx];     // gw is [EMBED][NE]
  }
  if (tid < NE) cnt[tid] = 0;
  __syncthreads();

  int lane = tid & 63, wv = tid >> 6;
  int t = blockIdx.x * 4 + wv;
  const float4* xr = (const float4*)(x + (size_t)t * EMBED);
  const float4* gt4 = (const float4*)gwt;
  float acc[NE];
  #pragma unroll
  for (int e = 0; e < NE; ++e) acc[e] = 0.f;
  #pragma unroll
  for (int c = 0; c < 4; ++c) {
    float4 xv = xr[c * 64 + lane];
    #pragma unroll
    for (int e = 0; e < NE; ++e) {
      float4 gv = gt4[e * 256 + c * 64 + lane];
      acc[e] += xv.x * gv.x + xv.y * gv.y + xv.z * gv.z + xv.w * gv.w;
    }
  }
  #pragma unroll
  for (int off = 1; off < 64; off <<= 1) {
    #pragma unroll
    for (int e = 0; e < NE; ++e) acc[e] += __shfl_xor(acc[e], off);
  }
  if (lane == 0) {
    int e0 = 0; float l0 = acc[0];
    #pragma unroll
    for (int e = 1; e < NE; ++e) if (acc[e] > l0) { l0 = acc[e]; e0 = e; }
    int e1 = -1; float l1 = -1e30f;
    #pragma unroll
    for (int e = 0; e < NE; ++e) if (e != e0 && acc[e] > l1) { l1 = acc[e]; e1 = e; }
    float w0 = 1.f / (1.f + expf(l1 - l0));   // softmax over {l0,l1}
    sel_e[2 * t] = e0;     sel_w[2 * t] = w0;
    sel_e[2 * t + 1] = e1; sel_w[2 * t + 1] = 1.f - w0;
    atomicAdd(&cnt[e0], 1); atomicAdd(&cnt[e1], 1);
  }
  __syncthreads();
  if (tid < NE && cnt[tid]) atomicAdd(&counts[tid], cnt[tid]);
}

// ---------------------------------------------------------------------------
// Offsets: 128-aligned segment starts per expert; cursor = start.
// ---------------------------------------------------------------------------
__global__ void offsets_kernel(const int* __restrict__ counts,
                               int* __restrict__ offs, int* __restrict__ cursor)
{
  if (threadIdx.x == 0) {
    int o = 0;
    for (int e = 0; e < NE; ++e) {
      offs[e] = o; cursor[e] = o;
      o += (counts[e] + 127) & ~127;
    }
    offs[NE] = o;
  }
}

// ---------------------------------------------------------------------------
// Assign: scatter (token, weight) into per-expert row lists. Wave-aggregated
// atomics.
// ---------------------------------------------------------------------------
__global__ __launch_bounds__(256) void assign_kernel(
    const int* __restrict__ sel_e, const float* __restrict__ sel_w,
    int* __restrict__ cursor, int* __restrict__ rowtok, float* __restrict__ rowcoef)
{
  int t = blockIdx.x * 256 + threadIdx.x;
  int lane = threadIdx.x & 63;
  #pragma unroll
  for (int k = 0; k < 2; ++k) {
    int e = sel_e[2 * t + k];
    float w = sel_w[2 * t + k];
    for (int xch = 0; xch < NE; ++xch) {
      unsigned long long m = __ballot(e == xch);
      if (e == xch) {
        int leader = __ffsll((unsigned long long)m) - 1;
        int base = 0;
        if (lane == leader) base = atomicAdd(&cursor[xch], (int)__popcll(m));
        base = __shfl(base, leader);
        int pos = base + (int)__popcll(m & ((1ull << lane) - 1));
        rowtok[pos] = t;
        rowcoef[pos] = w;
      }
    }
  }
}

// ---------------------------------------------------------------------------
// Gather: xg[row] = fp16(x[rowtok[row]]); zeros for padding rows (tok = -1).
// ---------------------------------------------------------------------------
__global__ __launch_bounds__(256) void gather_kernel(
    const float* __restrict__ x, const int* __restrict__ rowtok,
    _Float16* __restrict__ xg)
{
  int r = blockIdx.x;
  int tok = rowtok[r];
  int t4 = threadIdx.x * 4;
  _Float16* dst = xg + (size_t)r * EMBED + t4;
  if (tok >= 0) {
    float4 v = *(const float4*)(x + (size_t)tok * EMBED + t4);
    f16x4 h; h.x = (_Float16)v.x; h.y = (_Float16)v.y; h.z = (_Float16)v.z; h.w = (_Float16)v.w;
    *(f16x4*)dst = h;
  } else {
    f16x4 z = {(_Float16)0.f, (_Float16)0.f, (_Float16)0.f, (_Float16)0.f};
    *(f16x4*)dst = z;
  }
}

// ---------------------------------------------------------------------------
// Transpose+cast: in fp32 [K][N] -> out fp16 [N][K], per expert (blockIdx.z).
// ---------------------------------------------------------------------------
__global__ __launch_bounds__(256) void transpose_cast_kernel(
    const float* __restrict__ in, _Float16* __restrict__ out, int K, int N)
{
  const float* src = in + (size_t)blockIdx.z * K * N;
  _Float16* dst = out + (size_t)blockIdx.z * K * N;
  int k0 = blockIdx.x * 64, n0 = blockIdx.y * 64;
  __shared__ float tile[64][65];
  int t = threadIdx.x;
  int r = t >> 4, c4 = (t & 15) * 4;
  #pragma unroll
  for (int i = 0; i < 4; ++i) {
    float4 v = *(const float4*)(src + (size_t)(k0 + r + 16 * i) * N + n0 + c4);
    tile[r + 16 * i][c4 + 0] = v.x;
    tile[r + 16 * i][c4 + 1] = v.y;
    tile[r + 16 * i][c4 + 2] = v.z;
    tile[r + 16 * i][c4 + 3] = v.w;
  }
  __syncthreads();
  int kk8 = (t & 7) * 8, nIdx = t >> 3;
  #pragma unroll
  for (int i = 0; i < 2; ++i) {
    int n = nIdx + 32 * i;
    f16x8 h;
    #pragma unroll
    for (int j = 0; j < 8; ++j) h[j] = (_Float16)tile[kk8 + j][n];
    *(f16x8*)(dst + (size_t)(n0 + n) * K + k0 + kk8) = h;
  }
}

// ---------------------------------------------------------------------------
__device__ __forceinline__ int resolve_expert(const int* __restrict__ offs, int r0)
{
  int e = 0;
  #pragma unroll
  for (int q = 0; q < NE - 1; ++q) if (r0 >= offs[q + 1]) e = q + 1;
  return e;
}

// LDS tile geometry: 128 rows x 32 f16 (64 B/row) = 512 chunks of 16 B.
// Physical slot (row, kqp) holds logical k-quarter kql = kqp ^ ((row>>1)&3).
// Store: lane's LDS slot fixed at base+lane*16 (global_load_lds), lane fetches
// the swizzled global chunk. Read: phys = quad ^ ((row>>1)&3) -> each 8-lane
// phase covers all 32 banks exactly once (conflict-free ds_read_b128).
__device__ __forceinline__ const _Float16* frag_addr(const _Float16* buf, int row, int quad)
{
  return buf + row * 32 + ((quad ^ ((row >> 1) & 3)) << 3);
}

// ---------------------------------------------------------------------------
// GEMM1 (fused SwiGLU): h = silu(xg@w1t^T) * (xg@w3t^T) * coef, fp16 out.
// 128x128 tile, BK=32, global_load_lds staging, XOR-swizzled LDS.
// ---------------------------------------------------------------------------
__global__ __launch_bounds__(256, 2) void gemm1_kernel(
    const _Float16* __restrict__ xg, const _Float16* __restrict__ w1t,
    const _Float16* __restrict__ w3t, const float* __restrict__ rowcoef,
    const int* __restrict__ offs, _Float16* __restrict__ hb)
{
  int r0 = blockIdx.x * 128;
  if (r0 >= offs[NE]) return;
  int e = resolve_expert(offs, r0);
  int n0 = blockIdx.y * 128;
  const _Float16* B1 = w1t + (size_t)e * MLP * EMBED;
  const _Float16* B3 = w3t + (size_t)e * MLP * EMBED;

  __shared__ __align__(16) _Float16 As[128 * 32];
  __shared__ __align__(16) _Float16 Bs1[128 * 32];
  __shared__ __align__(16) _Float16 Bs3[128 * 32];

  int tid = threadIdx.x, lane = tid & 63, wv = tid >> 6;
  int wm = (wv & 1) << 6, wn = (wv >> 1) << 6;
  int l16 = lane & 15, quad = lane >> 4;

  f32x4 acc1[4][4], acc3[4][4];
  f32x4 z4 = {0.f, 0.f, 0.f, 0.f};
  #pragma unroll
  for (int i = 0; i < 4; ++i)
    #pragma unroll
    for (int j = 0; j < 4; ++j) { acc1[i][j] = z4; acc3[i][j] = z4; }

  for (int kk = 0; kk < EMBED; kk += 32) {
    __syncthreads();
    #pragma unroll
    for (int p = 0; p < 2; ++p) {
      int c = p * 256 + tid;                 // chunk this lane fetches
      int row = c >> 2, kqp = c & 3;
      int kql = kqp ^ ((row >> 1) & 3);      // swizzled logical k-quarter
      size_t gof = (size_t)(r0 + row) * EMBED + kk + kql * 8;
      size_t gofB = (size_t)(n0 + row) * EMBED + kk + kql * 8;
      int lof = (p * 256 + wv * 64) * 8;     // wave-uniform LDS base (f16 units)
      async_copy16(xg + gof,  As  + lof);
      async_copy16(B1 + gofB, Bs1 + lof);
      async_copy16(B3 + gofB, Bs3 + lof);
    }
    __syncthreads();
    f16x8 af[4], b1f[4], b3f[4];
    #pragma unroll
    for (int i = 0; i < 4; ++i)
      af[i] = *(const f16x8*)frag_addr(As, wm + 16 * i + l16, quad);
    #pragma unroll
    for (int j = 0; j < 4; ++j) {
      b1f[j] = *(const f16x8*)frag_addr(Bs1, wn + 16 * j + l16, quad);
      b3f[j] = *(const f16x8*)frag_addr(Bs3, wn + 16 * j + l16, quad);
    }
    #pragma unroll
    for (int i = 0; i < 4; ++i)
      #pragma unroll
      for (int j = 0; j < 4; ++j) {
        acc1[i][j] = __builtin_amdgcn_mfma_f32_16x16x32_f16(af[i], b1f[j], acc1[i][j], 0, 0, 0);
        acc3[i][j] = __builtin_amdgcn_mfma_f32_16x16x32_f16(af[i], b3f[j], acc3[i][j], 0, 0, 0);
      }
  }

  // Epilogue: h = silu(g)*u*coef[row]; C/D layout col=lane&15, row=quad*4+reg.
  #pragma unroll
  for (int i = 0; i < 4; ++i) {
    int mb = r0 + wm + 16 * i + quad * 4;
    float cf[4];
    #pragma unroll
    for (int rg = 0; rg < 4; ++rg) cf[rg] = rowcoef[mb + rg];
    #pragma unroll
    for (int j = 0; j < 4; ++j) {
      int col = n0 + wn + 16 * j + l16;
      #pragma unroll
      for (int rg = 0; rg < 4; ++rg) {
        float g = acc1[i][j][rg], u = acc3[i][j][rg];
        float h = g * u * cf[rg] / (1.f + __expf(-g));
        hb[(size_t)(mb + rg) * MLP + col] = (_Float16)h;
      }
    }
  }
}

// ---------------------------------------------------------------------------
// GEMM2: out[tok] += h @ w2t^T (w2t [n][k] fp16, K=2048). Scatter via fp32
// atomics (exactly 2 contributions per token).
// ---------------------------------------------------------------------------
__global__ __launch_bounds__(256, 2) void gemm2_kernel(
    const _Float16* __restrict__ hb, const _Float16* __restrict__ w2t,
    const int* __restrict__ rowtok, const int* __restrict__ offs,
    float* __restrict__ out)
{
  int r0 = blockIdx.x * 128;
  if (r0 >= offs[NE]) return;
  int e = resolve_expert(offs, r0);
  int n0 = blockIdx.y * 128;
  const _Float16* B = w2t + (size_t)e * EMBED * MLP;

  __shared__ __align__(16) _Float16 As[128 * 32];
  __shared__ __align__(16) _Float16 Bs[128 * 32];

  int tid = threadIdx.x, lane = tid & 63, wv = tid >> 6;
  int wm = (wv & 1) << 6, wn = (wv >> 1) << 6;
  int l16 = lane & 15, quad = lane >> 4;

  f32x4 acc[4][4];
  f32x4 z4 = {0.f, 0.f, 0.f, 0.f};
  #pragma unroll
  for (int i = 0; i < 4; ++i)
    #pragma unroll
    for (int j = 0; j < 4; ++j) acc[i][j] = z4;

  for (int kk = 0; kk < MLP; kk += 32) {
    __syncthreads();
    #pragma unroll
    for (int p = 0; p < 2; ++p) {
      int c = p * 256 + tid;
      int row = c >> 2, kqp = c & 3;
      int kql = kqp ^ ((row >> 1) & 3);
      size_t gofA = (size_t)(r0 + row) * MLP + kk + kql * 8;
      size_t gofB = (size_t)(n0 + row) * MLP + kk + kql * 8;
      int lof = (p * 256 + wv * 64) * 8;
      async_copy16(hb + gofA, As + lof);
      async_copy16(B  + gofB, Bs + lof);
    }
    __syncthreads();
    f16x8 af[4], bf[4];
    #pragma unroll
    for (int i = 0; i < 4; ++i)
      af[i] = *(const f16x8*)frag_addr(As, wm + 16 * i + l16, quad);
    #pragma unroll
    for (int j = 0; j < 4; ++j)
      bf[j] = *(const f16x8*)frag_addr(Bs, wn + 16 * j + l16, quad);
    #pragma unroll
    for (int i = 0; i < 4; ++i)
      #pragma unroll
      for (int j = 0; j < 4; ++j)
        acc[i][j] = __builtin_amdgcn_mfma_f32_16x16x32_f16(af[i], bf[j], acc[i][j], 0, 0, 0);
  }

  #pragma unroll
  for (int i = 0; i < 4; ++i) {
    int mb = r0 + wm + 16 * i + quad * 4;
    int tk[4];
    #pragma unroll
    for (int rg = 0; rg < 4; ++rg) tk[rg] = rowtok[mb + rg];
    #pragma unroll
    for (int j = 0; j < 4; ++j) {
      int col = n0 + wn + 16 * j + l16;
      #pragma unroll
      for (int rg = 0; rg < 4; ++rg)
        if (tk[rg] >= 0)
          atomicAdd(out + (size_t)tk[rg] * EMBED + col, acc[i][j][rg]);
    }
  }
}

// ---------------------------------------------------------------------------
extern "C" void kernel_launch(void* const* d_in, const int* in_sizes, int n_in,
                              void* d_out, int out_size, void* d_ws, size_t ws_size,
                              hipStream_t stream)
{
  (void)in_sizes; (void)n_in; (void)ws_size;
  const float* x  = (const float*)d_in[0];
  const float* gw = (const float*)d_in[1];
  const float* w1 = (const float*)d_in[2];
  const float* w2 = (const float*)d_in[3];   // NOTE: dict order is w1, w2, w3
  const float* w3 = (const float*)d_in[4];
  float* out = (float*)d_out;
  char* ws = (char*)d_ws;

  size_t o = 0;
  auto alloc = [&](size_t bytes) { size_t r = o; o = (o + bytes + 255) & ~255ULL; return r; };
  const size_t wbytes = (size_t)NE * MLP * EMBED * 2;
  _Float16* w1t = (_Float16*)(ws + alloc(wbytes));
  _Float16* w3t = (_Float16*)(ws + alloc(wbytes));
  _Float16* w2t = (_Float16*)(ws + alloc(wbytes));
  _Float16* xg  = (_Float16*)(ws + alloc((size_t)RMAX * EMBED * 2));
  _Float16* hb  = (_Float16*)(ws + alloc((size_t)RMAX * MLP * 2));
  int*   rowtok  = (int*)(ws + alloc((size_t)RMAX * 4));
  float* rowcoef = (float*)(ws + alloc((size_t)RMAX * 4));
  int*   sel_e   = (int*)(ws + alloc((size_t)2 * NTOK * 4));
  float* sel_w   = (float*)(ws + alloc((size_t)2 * NTOK * 4));
  int*   meta    = (int*)(ws + alloc(256));
  int* counts = meta;          // [8]
  int* offs   = meta + 8;      // [9]
  int* cursor = meta + 17;     // [8]

  hipMemsetAsync(out, 0, (size_t)out_size * 4, stream);
  hipMemsetAsync(meta, 0, 256, stream);
  hipMemsetAsync(rowtok, 0xFF, (size_t)RMAX * 4, stream);   // -1 = padding
  hipMemsetAsync(rowcoef, 0, (size_t)RMAX * 4, stream);

  transpose_cast_kernel<<<dim3(EMBED / 64, MLP / 64, NE), 256, 0, stream>>>(w1, w1t, EMBED, MLP);
  transpose_cast_kernel<<<dim3(EMBED / 64, MLP / 64, NE), 256, 0, stream>>>(w3, w3t, EMBED, MLP);
  transpose_cast_kernel<<<dim3(MLP / 64, EMBED / 64, NE), 256, 0, stream>>>(w2, w2t, MLP, EMBED);

  router_kernel<<<NTOK / 4, 256, 0, stream>>>(x, gw, sel_e, sel_w, counts);
  offsets_kernel<<<1, 64, 0, stream>>>(counts, offs, cursor);
  assign_kernel<<<NTOK / 256, 256, 0, stream>>>(sel_e, sel_w, cursor, rowtok, rowcoef);
  gather_kernel<<<RMAX, 256, 0, stream>>>(x, rowtok, xg);

  gemm1_kernel<<<dim3(RMAX / 128, MLP / 128), 256, 0, stream>>>(xg, w1t, w3t, rowcoef, offs, hb);
  gemm2_kernel<<<dim3(RMAX / 128, EMBED / 128), 256, 0, stream>>>(hb, w2t, rowtok, offs, out);
}